// Round 6
// baseline (242.993 us; speedup 1.0000x reference)
//
#include <hip/hip_runtime.h>

// Octree cross-entropy loss.
// D=256, BS=16 -> 4096 level-0 tiles of 16^3 voxels.
// Level 0: per-voxel 2-class CE, mean over tile, summed over tiles.
// Levels 1..4 (b = 32,64,128,256): 3-class CE (pure0/pure1/mixed) * b^3,
// class derived from per-16^3-tile popcounts of gt01 aggregated upward.
//
// R8 -> R9 changes:
//  - Every prior version (R3..R8, incl. the exact m13 copy shape in R8)
//    pinned at 1.65-1.9 TB/s. The one structural constant: a SECOND stream
//    interleaved into the hot loop -- the gt int4 load, which per wave
//    scatters 16x64B segments over 16 KB (LLC-served, high latency, TA
//    split) between every pair of streaming logits loads.
//  - R9 removes it: K0 (gt_pack) linearly reads gt (int4, coalesced) and
//    packs the +-1 signs into a 2 MiB bitmask (bit g = gt01 of linear voxel
//    g; nibble-aligned so 4 consecutive z = one nibble). K1 (level0) is R8
//    with the gt load replaced by one L2-resident u32 mask word per 4 lanes
//    (broadcast) -- hot loop is now a pure dual linear fp32 stream.
//  - nontemporal qualifiers dropped: match the proven plain-float4 copy
//    shape exactly.

typedef float v4f __attribute__((ext_vector_type(4)));

__device__ __forceinline__ float softplus(float x) {
    // log(1 + e^x), stable
    return fmaxf(x, 0.f) + __logf(1.f + __expf(-fabsf(x)));
}

__device__ __forceinline__ float nll3(const float* __restrict__ l, int c) {
    float a = l[0], b = l[1], d = l[2];
    float m = fmaxf(fmaxf(a, b), d);
    float lse = m + __logf(__expf(a - m) + __expf(b - m) + __expf(d - m));
    return lse - l[c];
}

// ---- K0: pack gt (+-1 int32) -> bitmask, 1 bit per voxel, linear order ----
// unit u = 4 consecutive voxels (one int4). Word w = mask[u>>3] holds units
// 8w..8w+7, unit's nibble at bits 4*(u&7)..+3, bit k of nibble = voxel 4u+k.
__global__ __launch_bounds__(256, 8) void gt_pack_kernel(
    const int* __restrict__ gt,            // [256^3], values +-1
    unsigned int* __restrict__ mask)       // [524288] packed gt01 bits
{
    const int tid0 = blockIdx.x * 256 + threadIdx.x;
    const int lane = threadIdx.x & 63;
    constexpr int NTH = 2048 * 256;        // 524288 threads, 8 units each

#pragma unroll
    for (int it = 0; it < 8; ++it) {
        const int u = it * NTH + tid0;
        const int4 g = *reinterpret_cast<const int4*>(gt + (size_t)u * 4);
        unsigned int v = (unsigned int)(g.x > 0)
                       | ((unsigned int)(g.y > 0) << 1)
                       | ((unsigned int)(g.z > 0) << 2)
                       | ((unsigned int)(g.w > 0) << 3);
        // pack 8 lanes' nibbles into one u32 on lanes l%8==0
        v |= __shfl_down(v, 1, 64) << 4;
        v |= __shfl_down(v, 2, 64) << 8;
        v |= __shfl_down(v, 4, 64) << 16;
        if ((lane & 7) == 0) mask[u >> 3] = v;
    }
}

// ---- K1: 2048 blocks x 256 threads = 8192 waves; wave W owns half-tile
// (tile = W>>1, half = W&1): 8 iterations x 64 lanes x 4 voxels. Pure dual
// linear logits stream + one L2 mask word per 4 lanes. ----
__global__ __launch_bounds__(256, 8) void level0_kernel(
    const float* __restrict__ logits,      // [4096, 2, 4096]
    const unsigned int* __restrict__ mask, // [524288] packed gt01
    float* __restrict__ partial2,          // [2][4096] slot-major NLL sums
    int* __restrict__ cnt2)                // [2][4096] slot-major popcounts
{
    const int lane = threadIdx.x & 63;
    const int W    = blockIdx.x * 4 + (threadIdx.x >> 6);  // 0..8191
    const int tile = W >> 1;
    const int half = W & 1;

    // logits: half h covers float4-units [h*512, h*512+512) of the tile
    const float* aptr = logits + (size_t)tile * 8192 + half * 2048;
    const float* bptr = aptr + 4096;

    // voxel of (i, lane): ix = 8*half+i, iy = lane>>2, iz = 4*(lane&3)
    // global g = (bx*16+ix)<<16 | (by*16+iy)<<8 | (bz*16+iz); unit u = g>>2
    // word = (x<<11) + (y<<3) + (bz>>1); nibble index = 4*(bz&1) + (lane&3)
    const int bx = tile >> 8, by = (tile >> 4) & 15, bz = tile & 15;
    const int wbase = ((bx * 16 + half * 8) << 11)
                    + ((by * 16 + (lane >> 2)) << 3) + (bz >> 1);
    const int shift = ((bz & 1) << 4) + ((lane & 3) << 2);

    float ls = 0.f;
    int   on = 0;
#pragma unroll
    for (int i = 0; i < 8; ++i) {
        const v4f a = *reinterpret_cast<const v4f*>(aptr + (i * 64 + lane) * 4);
        const v4f b = *reinterpret_cast<const v4f*>(bptr + (i * 64 + lane) * 4);
        const unsigned int nib = (mask[wbase + (i << 11)] >> shift) & 0xFu;

        // 2-class CE: tgt=1 -> softplus(l0-l1); tgt=0 -> softplus(l1-l0)
        const float dx = a.x - b.x;
        const float dy = a.y - b.y;
        const float dz = a.z - b.z;
        const float dw = a.w - b.w;
        on += __popc(nib);
        ls += softplus((nib & 1u) ? dx : -dx)
            + softplus((nib & 2u) ? dy : -dy)
            + softplus((nib & 4u) ? dz : -dz)
            + softplus((nib & 8u) ? dw : -dw);
    }

    // one wave reduce, one write per half-tile (each slot written exactly once)
#pragma unroll
    for (int d = 32; d > 0; d >>= 1) {
        ls += __shfl_down(ls, d, 64);
        on += __shfl_down(on, d, 64);
    }
    if (lane == 0) {
        partial2[half * 4096 + tile] = ls * (1.0f / 4096.0f);
        cnt2[half * 4096 + tile]     = on;
    }
}

// Single block, 512 threads: fold 2 slots (coalesced), reduce level-0
// partials, hierarchical popcount aggregation, 3-class CE levels 1..4.
__global__ __launch_bounds__(512) void levels_kernel(
    const float* __restrict__ partial2, // [2][4096]
    const int* __restrict__ cnt2,       // [2][4096]
    const float* __restrict__ l1,       // [512,3]
    const float* __restrict__ l2,       // [64,3]
    const float* __restrict__ l3,       // [8,3]
    const float* __restrict__ l4,       // [1,3]
    float* __restrict__ out)
{
    __shared__ int   s0[4096];   // per-tile popcounts (16 KB)
    __shared__ int   s1[512];
    __shared__ int   s2[64];
    __shared__ int   s3[8];
    __shared__ float red[512];
    const int tid = threadIdx.x;
    float contrib = 0.f;

    // fold 2 slots per tile; 8 tiles per thread via 2x float4/int4 per slot
#pragma unroll
    for (int j = 0; j < 2; ++j) {
        const int t = tid * 8 + j * 4;
        const float4 p0 = *reinterpret_cast<const float4*>(partial2 + t);
        const float4 p1 = *reinterpret_cast<const float4*>(partial2 + 4096 + t);
        const int4   c0 = *reinterpret_cast<const int4*>(cnt2 + t);
        const int4   c1 = *reinterpret_cast<const int4*>(cnt2 + 4096 + t);
        contrib += (p0.x + p1.x) + (p0.y + p1.y) + (p0.z + p1.z) + (p0.w + p1.w);
        s0[t + 0] = c0.x + c1.x;
        s0[t + 1] = c0.y + c1.y;
        s0[t + 2] = c0.z + c1.z;
        s0[t + 3] = c0.w + c1.w;
    }
    __syncthreads();

    // level 1: 8^3 blocks, each aggregates 2^3 level-0 tiles (16^3 grid)
    {
        const int X = tid >> 6, Y = (tid >> 3) & 7, Z = tid & 7;
        int s = 0;
#pragma unroll
        for (int dx = 0; dx < 2; ++dx)
#pragma unroll
            for (int dy = 0; dy < 2; ++dy)
#pragma unroll
                for (int dz = 0; dz < 2; ++dz)
                    s += s0[((X * 2 + dx) * 16 + (Y * 2 + dy)) * 16 + (Z * 2 + dz)];
        s1[tid] = s;
        const int tot = 8 * 4096;
        const int c = (s == 0) ? 0 : ((s == tot) ? 1 : 2);
        contrib += nll3(l1 + tid * 3, c) * 32768.0f;      // 32^3
    }
    __syncthreads();
    // level 2: 4^3 blocks from 8^3 grid
    if (tid < 64) {
        const int X = tid >> 4, Y = (tid >> 2) & 3, Z = tid & 3;
        int s = 0;
#pragma unroll
        for (int dx = 0; dx < 2; ++dx)
#pragma unroll
            for (int dy = 0; dy < 2; ++dy)
#pragma unroll
                for (int dz = 0; dz < 2; ++dz)
                    s += s1[((X * 2 + dx) * 8 + (Y * 2 + dy)) * 8 + (Z * 2 + dz)];
        s2[tid] = s;
        const int tot = 64 * 4096;
        const int c = (s == 0) ? 0 : ((s == tot) ? 1 : 2);
        contrib += nll3(l2 + tid * 3, c) * 262144.0f;     // 64^3
    }
    __syncthreads();
    // level 3: 2^3 blocks from 4^3 grid
    if (tid < 8) {
        const int X = tid >> 2, Y = (tid >> 1) & 1, Z = tid & 1;
        int s = 0;
#pragma unroll
        for (int dx = 0; dx < 2; ++dx)
#pragma unroll
            for (int dy = 0; dy < 2; ++dy)
#pragma unroll
                for (int dz = 0; dz < 2; ++dz)
                    s += s2[((X * 2 + dx) * 4 + (Y * 2 + dy)) * 4 + (Z * 2 + dz)];
        s3[tid] = s;
        const int tot = 512 * 4096;
        const int c = (s == 0) ? 0 : ((s == tot) ? 1 : 2);
        contrib += nll3(l3 + tid * 3, c) * 2097152.0f;    // 128^3
    }
    __syncthreads();
    // level 4: 1 block = everything
    if (tid == 0) {
        int s = 0;
#pragma unroll
        for (int i = 0; i < 8; ++i) s += s3[i];
        const int tot = 4096 * 4096;
        const int c = (s == 0) ? 0 : ((s == tot) ? 1 : 2);
        contrib += nll3(l4, c) * 16777216.0f;             // 256^3
    }

    red[tid] = contrib;
    __syncthreads();
#pragma unroll
    for (int s = 256; s > 0; s >>= 1) {
        if (tid < s) red[tid] += red[tid + s];
        __syncthreads();
    }
    if (tid == 0) out[0] = red[0];
}

extern "C" void kernel_launch(void* const* d_in, const int* in_sizes, int n_in,
                              void* d_out, int out_size, void* d_ws, size_t ws_size,
                              hipStream_t stream) {
    const int*   gt    = (const int*)d_in[0];
    const float* dense = (const float*)d_in[1];
    const float* l1    = (const float*)d_in[2];
    const float* l2    = (const float*)d_in[3];
    const float* l3    = (const float*)d_in[4];
    const float* l4    = (const float*)d_in[5];
    float* out = (float*)d_out;

    unsigned int* mask = (unsigned int*)d_ws;        // 524288 u32 (2 MiB)
    float* partial2 = (float*)(mask + 524288);       // [2][4096] floats
    int*   cnt2     = (int*)(partial2 + 8192);       // [2][4096] ints

    gt_pack_kernel<<<2048, 256, 0, stream>>>(gt, mask);
    level0_kernel<<<2048, 256, 0, stream>>>(dense, mask, partial2, cnt2);
    levels_kernel<<<1, 512, 0, stream>>>(partial2, cnt2, l1, l2, l3, l4, out);
}

// Round 7
// 242.277 us; speedup vs baseline: 1.0030x; 1.0030x over previous
//
#include <hip/hip_runtime.h>

// Octree cross-entropy loss.
// D=256, BS=16 -> 4096 level-0 tiles of 16^3 voxels.
// Level 0: per-voxel 2-class CE, mean over tile, summed over tiles.
// Levels 1..4 (b = 32,64,128,256): 3-class CE (pure0/pure1/mixed) * b^3,
// class derived from per-16^3-tile popcounts of gt01 aggregated upward.
//
// R9 -> R10:
//  - All register-load shapes pin at ~2.2-2.6 TB/s read. Little's law points
//    at effective outstanding-reads/CU of only ~8 KB: the allocator never
//    sustains a deep per-wave read pipeline (8 iters of data = 72 VGPR > the
//    64-VGPR occupancy cap). R10 tests the one untried mechanism: wave-
//    private LDS-DMA ring (global_load_lds = no dest VGPRs) with COUNTED
//    vmcnt waits and zero barriers. R6 tried this but a late register copy
//    degenerated it to vmcnt(0); this version's hot loop has NO register-
//    returning loads (gt comes from the R9 bitmask, hoisted before the ring)
//    so the counted waits are provably robust.
//  - Ring: 3 x 2 KB wave-private buffers; steady state keeps 2 slices
//    (4 x 1 KB DMA) in flight per wave -> ~96 KB/CU outstanding by
//    construction. lgkmcnt(0) before restaging a consumed buffer;
//    sched_barrier(0) after each vmcnt wait (rule #18).

typedef float v4f __attribute__((ext_vector_type(4)));

__device__ __forceinline__ float softplus(float x) {
    // log(1 + e^x), stable
    return fmaxf(x, 0.f) + __logf(1.f + __expf(-fabsf(x)));
}

__device__ __forceinline__ float nll3(const float* __restrict__ l, int c) {
    float a = l[0], b = l[1], d = l[2];
    float m = fmaxf(fmaxf(a, b), d);
    float lse = m + __logf(__expf(a - m) + __expf(b - m) + __expf(d - m));
    return lse - l[c];
}

// HBM -> LDS direct DMA, 16 B per lane. Dest is wave-uniform base + lane*16.
#define GLOAD_LDS16(gsrc, ldst)                                                \
    __builtin_amdgcn_global_load_lds(                                          \
        (const __attribute__((address_space(1))) void*)(gsrc),                 \
        (__attribute__((address_space(3))) void*)(ldst), 16, 0, 0)

// ---- K0: pack gt (+-1 int32) -> bitmask, 1 bit per voxel, linear order ----
// unit u = 4 consecutive voxels (one int4). Word w = mask[u>>3] holds units
// 8w..8w+7, unit's nibble at bits 4*(u&7)..+3, bit k of nibble = voxel 4u+k.
__global__ __launch_bounds__(256, 8) void gt_pack_kernel(
    const int* __restrict__ gt,            // [256^3], values +-1
    unsigned int* __restrict__ mask)       // [524288] packed gt01 bits
{
    const int tid0 = blockIdx.x * 256 + threadIdx.x;
    const int lane = threadIdx.x & 63;
    constexpr int NTH = 2048 * 256;        // 524288 threads, 8 units each

#pragma unroll
    for (int it = 0; it < 8; ++it) {
        const int u = it * NTH + tid0;
        const int4 g = *reinterpret_cast<const int4*>(gt + (size_t)u * 4);
        unsigned int v = (unsigned int)(g.x > 0)
                       | ((unsigned int)(g.y > 0) << 1)
                       | ((unsigned int)(g.z > 0) << 2)
                       | ((unsigned int)(g.w > 0) << 3);
        // pack 8 lanes' nibbles into one u32 on lanes l%8==0
        v |= __shfl_down(v, 1, 64) << 4;
        v |= __shfl_down(v, 2, 64) << 8;
        v |= __shfl_down(v, 4, 64) << 16;
        if ((lane & 7) == 0) mask[u >> 3] = v;
    }
}

// ---- K1: 2048 blocks x 256 threads = 8192 waves; wave W owns half-tile
// (tile = W>>1, half = W&1): 8 slices x (1 KB a + 1 KB b), DMA ring depth 3.
__global__ __launch_bounds__(256, 6) void level0_kernel(
    const float* __restrict__ logits,      // [4096, 2, 4096]
    const unsigned int* __restrict__ mask, // [524288] packed gt01
    float* __restrict__ partial2,          // [2][4096] slot-major NLL sums
    int* __restrict__ cnt2)                // [2][4096] slot-major popcounts
{
    __shared__ float ring[4][3][512];      // [wave][buf][a(256)|b(256)]

    const int lane = threadIdx.x & 63;
    const int wave = threadIdx.x >> 6;
    const int W    = blockIdx.x * 4 + wave;  // 0..8191
    const int tile = W >> 1;
    const int half = W & 1;

    // logits: half h covers float4-units [h*512, h*512+512) of the tile
    const float* aptr = logits + (size_t)tile * 8192 + half * 2048;
    const float* bptr = aptr + 4096;

    // voxel of (slice i, lane): ix = 8*half+i, iy = lane>>2, iz = 4*(lane&3)
    // mask word = (x<<11) + (y<<3) + (bz>>1); nibble shift below.
    const int bx = tile >> 8, by = (tile >> 4) & 15, bz = tile & 15;
    const int wbase = ((bx * 16 + half * 8) << 11)
                    + ((by * 16 + (lane >> 2)) << 3) + (bz >> 1);
    const int shift = ((bz & 1) << 4) + ((lane & 3) << 2);

    // hoist all 8 mask words (L2-resident, 8 VGPR). Their vmcnt slots are
    // covered by the ring waits regardless of where the compiler issues them
    // (waits below are valid under any interleaving; see FIFO analysis).
    unsigned int m[8];
#pragma unroll
    for (int i = 0; i < 8; ++i) m[i] = mask[wbase + (i << 11)];

    float* const B0 = &ring[wave][0][0];
    float* const B1 = &ring[wave][1][0];
    float* const B2 = &ring[wave][2][0];

    // slice i: a-floats [i*256, +256), b-floats same offset in b-plane
#define STAGE(dst, i)                                                          \
    do {                                                                       \
        GLOAD_LDS16(aptr + (i) * 256 + lane * 4, (dst));                       \
        GLOAD_LDS16(bptr + (i) * 256 + lane * 4, (dst) + 256);                 \
    } while (0)

    STAGE(B0, 0);
    STAGE(B1, 1);
    STAGE(B2, 2);

    float ls = 0.f;
    int   on = 0;
#pragma unroll
    for (int s = 0; s < 8; ++s) {
        // ensure slice s's 2 DMA ops are done; keep later slices in flight
        if (s <= 5)      asm volatile("s_waitcnt vmcnt(4)" ::: "memory");
        else if (s == 6) asm volatile("s_waitcnt vmcnt(2)" ::: "memory");
        else             asm volatile("s_waitcnt vmcnt(0)" ::: "memory");
        __builtin_amdgcn_sched_barrier(0);

        float* const lb = (s % 3 == 0) ? B0 : ((s % 3 == 1) ? B1 : B2);
        const v4f a = *reinterpret_cast<const v4f*>(lb + lane * 4);
        const v4f b = *reinterpret_cast<const v4f*>(lb + 256 + lane * 4);
        const unsigned int nib = (m[s] >> shift) & 0xFu;

        // 2-class CE: tgt=1 -> softplus(l0-l1); tgt=0 -> softplus(l1-l0)
        const float dx = a.x - b.x;
        const float dy = a.y - b.y;
        const float dz = a.z - b.z;
        const float dw = a.w - b.w;
        on += __popc(nib);
        ls += softplus((nib & 1u) ? dx : -dx)
            + softplus((nib & 2u) ? dy : -dy)
            + softplus((nib & 4u) ? dz : -dz)
            + softplus((nib & 8u) ? dw : -dw);

        if (s + 3 < 8) {
            // restage the buffer just consumed ((s+3)%3 == s%3). The LDS
            // reads above must have retired before the DMA can overwrite:
            asm volatile("s_waitcnt lgkmcnt(0)" ::: "memory");
            __builtin_amdgcn_sched_barrier(0);
            STAGE(lb, s + 3);
        }
    }
#undef STAGE

    // one wave reduce, one write per half-tile (each slot written exactly once)
#pragma unroll
    for (int d = 32; d > 0; d >>= 1) {
        ls += __shfl_down(ls, d, 64);
        on += __shfl_down(on, d, 64);
    }
    if (lane == 0) {
        partial2[half * 4096 + tile] = ls * (1.0f / 4096.0f);
        cnt2[half * 4096 + tile]     = on;
    }
}

// Single block, 512 threads: fold 2 slots (coalesced), reduce level-0
// partials, hierarchical popcount aggregation, 3-class CE levels 1..4.
__global__ __launch_bounds__(512) void levels_kernel(
    const float* __restrict__ partial2, // [2][4096]
    const int* __restrict__ cnt2,       // [2][4096]
    const float* __restrict__ l1,       // [512,3]
    const float* __restrict__ l2,       // [64,3]
    const float* __restrict__ l3,       // [8,3]
    const float* __restrict__ l4,       // [1,3]
    float* __restrict__ out)
{
    __shared__ int   s0[4096];   // per-tile popcounts (16 KB)
    __shared__ int   s1[512];
    __shared__ int   s2[64];
    __shared__ int   s3[8];
    __shared__ float red[512];
    const int tid = threadIdx.x;
    float contrib = 0.f;

    // fold 2 slots per tile; 8 tiles per thread via 2x float4/int4 per slot
#pragma unroll
    for (int j = 0; j < 2; ++j) {
        const int t = tid * 8 + j * 4;
        const float4 p0 = *reinterpret_cast<const float4*>(partial2 + t);
        const float4 p1 = *reinterpret_cast<const float4*>(partial2 + 4096 + t);
        const int4   c0 = *reinterpret_cast<const int4*>(cnt2 + t);
        const int4   c1 = *reinterpret_cast<const int4*>(cnt2 + 4096 + t);
        contrib += (p0.x + p1.x) + (p0.y + p1.y) + (p0.z + p1.z) + (p0.w + p1.w);
        s0[t + 0] = c0.x + c1.x;
        s0[t + 1] = c0.y + c1.y;
        s0[t + 2] = c0.z + c1.z;
        s0[t + 3] = c0.w + c1.w;
    }
    __syncthreads();

    // level 1: 8^3 blocks, each aggregates 2^3 level-0 tiles (16^3 grid)
    {
        const int X = tid >> 6, Y = (tid >> 3) & 7, Z = tid & 7;
        int s = 0;
#pragma unroll
        for (int dx = 0; dx < 2; ++dx)
#pragma unroll
            for (int dy = 0; dy < 2; ++dy)
#pragma unroll
                for (int dz = 0; dz < 2; ++dz)
                    s += s0[((X * 2 + dx) * 16 + (Y * 2 + dy)) * 16 + (Z * 2 + dz)];
        s1[tid] = s;
        const int tot = 8 * 4096;
        const int c = (s == 0) ? 0 : ((s == tot) ? 1 : 2);
        contrib += nll3(l1 + tid * 3, c) * 32768.0f;      // 32^3
    }
    __syncthreads();
    // level 2: 4^3 blocks from 8^3 grid
    if (tid < 64) {
        const int X = tid >> 4, Y = (tid >> 2) & 3, Z = tid & 3;
        int s = 0;
#pragma unroll
        for (int dx = 0; dx < 2; ++dx)
#pragma unroll
            for (int dy = 0; dy < 2; ++dy)
#pragma unroll
                for (int dz = 0; dz < 2; ++dz)
                    s += s1[((X * 2 + dx) * 8 + (Y * 2 + dy)) * 8 + (Z * 2 + dz)];
        s2[tid] = s;
        const int tot = 64 * 4096;
        const int c = (s == 0) ? 0 : ((s == tot) ? 1 : 2);
        contrib += nll3(l2 + tid * 3, c) * 262144.0f;     // 64^3
    }
    __syncthreads();
    // level 3: 2^3 blocks from 4^3 grid
    if (tid < 8) {
        const int X = tid >> 2, Y = (tid >> 1) & 1, Z = tid & 1;
        int s = 0;
#pragma unroll
        for (int dx = 0; dx < 2; ++dx)
#pragma unroll
            for (int dy = 0; dy < 2; ++dy)
#pragma unroll
                for (int dz = 0; dz < 2; ++dz)
                    s += s2[((X * 2 + dx) * 4 + (Y * 2 + dy)) * 4 + (Z * 2 + dz)];
        s3[tid] = s;
        const int tot = 512 * 4096;
        const int c = (s == 0) ? 0 : ((s == tot) ? 1 : 2);
        contrib += nll3(l3 + tid * 3, c) * 2097152.0f;    // 128^3
    }
    __syncthreads();
    // level 4: 1 block = everything
    if (tid == 0) {
        int s = 0;
#pragma unroll
        for (int i = 0; i < 8; ++i) s += s3[i];
        const int tot = 4096 * 4096;
        const int c = (s == 0) ? 0 : ((s == tot) ? 1 : 2);
        contrib += nll3(l4, c) * 16777216.0f;             // 256^3
    }

    red[tid] = contrib;
    __syncthreads();
#pragma unroll
    for (int s = 256; s > 0; s >>= 1) {
        if (tid < s) red[tid] += red[tid + s];
        __syncthreads();
    }
    if (tid == 0) out[0] = red[0];
}

extern "C" void kernel_launch(void* const* d_in, const int* in_sizes, int n_in,
                              void* d_out, int out_size, void* d_ws, size_t ws_size,
                              hipStream_t stream) {
    const int*   gt    = (const int*)d_in[0];
    const float* dense = (const float*)d_in[1];
    const float* l1    = (const float*)d_in[2];
    const float* l2    = (const float*)d_in[3];
    const float* l3    = (const float*)d_in[4];
    const float* l4    = (const float*)d_in[5];
    float* out = (float*)d_out;

    unsigned int* mask = (unsigned int*)d_ws;        // 524288 u32 (2 MiB)
    float* partial2 = (float*)(mask + 524288);       // [2][4096] floats
    int*   cnt2     = (int*)(partial2 + 8192);       // [2][4096] ints

    gt_pack_kernel<<<2048, 256, 0, stream>>>(gt, mask);
    level0_kernel<<<2048, 256, 0, stream>>>(dense, mask, partial2, cnt2);
    levels_kernel<<<1, 512, 0, stream>>>(partial2, cnt2, l1, l2, l3, l4, out);
}